// Round 1
// baseline (11633.906 us; speedup 1.0000x reference)
//
#include <hip/hip_runtime.h>

#define NN 50000
#define NE 800000

// ---------------- degree kernels ----------------
__global__ void k_deg_init(float* a, float* b, int n) {
    int i = blockIdx.x * 256 + threadIdx.x;
    if (i < n) { a[i] = 1.0f; b[i] = 1.0f; }
}

__global__ void k_deg_count(const int* __restrict__ dst, const int* __restrict__ dstb,
                            float* __restrict__ deg, float* __restrict__ degb, int e) {
    int i = blockIdx.x * 256 + threadIdx.x;
    if (i < e) {
        atomicAdd(&deg[dst[i]], 1.0f);
        atomicAdd(&degb[dstb[i]], 1.0f);
    }
}

__global__ void k_deg_fin(float* dinv, float* deginv, float* dinvb, float* deginvb, int n) {
    int i = blockIdx.x * 256 + threadIdx.x;
    if (i < n) {
        float d = dinv[i];
        dinv[i]   = rsqrtf(d);
        deginv[i] = 1.0f / d;
        float db = dinvb[i];
        dinvb[i]   = rsqrtf(db);
        deginvb[i] = 1.0f / db;
    }
}

// ---------------- permute / mix ----------------
__global__ void k_permute(const float4* __restrict__ in, const int* __restrict__ perm,
                          float4* __restrict__ out, int n) {
    int t = blockIdx.x * 256 + threadIdx.x;
    if (t < n * 32) {
        int i = t >> 5, c = t & 31;
        out[t] = in[perm[i] * 32 + c];
    }
}

__global__ void k_mixcomb(const float4* __restrict__ a, const float4* __restrict__ b,
                          const float* __restrict__ lamp, float4* __restrict__ o, int n4) {
    int t = blockIdx.x * 256 + threadIdx.x;
    if (t < n4) {
        float lam = lamp[0], ml = 1.0f - lam;
        float4 va = a[t], vb = b[t];
        o[t] = make_float4(fmaf(lam, va.x, ml * vb.x),
                           fmaf(lam, va.y, ml * vb.y),
                           fmaf(lam, va.z, ml * vb.z),
                           fmaf(lam, va.w, ml * vb.w));
    }
}

// ---------------- edge scatter (segment_sum via atomics) ----------------
// 32 threads per edge, float4 per thread.
__global__ void k_scatter(const float* __restrict__ xsrc, const int* __restrict__ src,
                          const int* __restrict__ dst, const float* __restrict__ dinv,
                          float* __restrict__ agg, int e) {
    int t = blockIdx.x * 256 + threadIdx.x;
    int eid = t >> 5, c4 = t & 31;
    if (eid < e) {
        int s = src[eid], d = dst[eid];
        float w = dinv[s] * dinv[d];
        float4 v = ((const float4*)xsrc)[s * 32 + c4];
        float* ap = agg + (d * 128 + c4 * 4);
        atomicAdd(ap + 0, v.x * w);
        atomicAdd(ap + 1, v.y * w);
        atomicAdd(ap + 2, v.z * w);
        atomicAdd(ap + 3, v.w * w);
    }
}

// ---------------- fused (S + self*deginv) @ W + b, relu ----------------
// Block = 256 threads, 64 rows per block in 8-row tiles.
// Each thread: 1 column (j = tid&127), 4 rows (h = tid>>7 selects half of tile).
// In-place safe (out may alias S): rows staged to LDS before any write.
__global__ __launch_bounds__(256) void k_mm_relu(
    const float* __restrict__ S, const float* __restrict__ selfx,
    const float* __restrict__ deginv, const float* __restrict__ W,
    const float* __restrict__ bias, float* __restrict__ out, int rows) {
    __shared__ __align__(16) float Wl[128 * 128];   // 64 KiB
    __shared__ __align__(16) float rb[8][128];
    int tid = threadIdx.x;
#pragma unroll
    for (int i = 0; i < 16; ++i)
        ((float4*)Wl)[tid + i * 256] = ((const float4*)W)[tid + i * 256];
    int j = tid & 127, h = tid >> 7;
    int base = blockIdx.x * 64;
    __syncthreads();
    for (int t = 0; t < 8; ++t) {
        int r0 = base + t * 8;
        {   // stage 8 rows: row = S[row] + selfx[row]*deginv[row]
            int rr = tid >> 5, cc = tid & 31;
            int gi = r0 + rr;
            float4 rv = make_float4(0.f, 0.f, 0.f, 0.f);
            if (gi < rows) {
                float4 sv = ((const float4*)S)[gi * 32 + cc];
                float4 xv = ((const float4*)selfx)[gi * 32 + cc];
                float di = deginv[gi];
                rv = make_float4(fmaf(xv.x, di, sv.x), fmaf(xv.y, di, sv.y),
                                 fmaf(xv.z, di, sv.z), fmaf(xv.w, di, sv.w));
            }
            *((float4*)&rb[rr][cc * 4]) = rv;
        }
        __syncthreads();
        float bv = bias[j];
        float a0 = bv, a1 = bv, a2 = bv, a3 = bv;
#pragma unroll
        for (int k = 0; k < 128; ++k) {
            float wv = Wl[k * 128 + j];
            a0 = fmaf(rb[h * 4 + 0][k], wv, a0);
            a1 = fmaf(rb[h * 4 + 1][k], wv, a1);
            a2 = fmaf(rb[h * 4 + 2][k], wv, a2);
            a3 = fmaf(rb[h * 4 + 3][k], wv, a3);
        }
        int gi = r0 + h * 4;
        if (gi + 0 < rows) out[(gi + 0) * 128 + j] = fmaxf(a0, 0.f);
        if (gi + 1 < rows) out[(gi + 1) * 128 + j] = fmaxf(a1, 0.f);
        if (gi + 2 < rows) out[(gi + 2) * 128 + j] = fmaxf(a2, 0.f);
        if (gi + 3 < rows) out[(gi + 3) * 128 + j] = fmaxf(a3, 0.f);
        __syncthreads();
    }
}

// ---------------- final linear [128->64] + log_softmax ----------------
// One wave per node, lane = output class.
__global__ __launch_bounds__(256) void k_lin_lsm(
    const float* __restrict__ X, const float* __restrict__ Wlin,
    const float* __restrict__ blin, float* __restrict__ out, int rows) {
    __shared__ __align__(16) float Wl[128 * 64];    // 32 KiB
    __shared__ float rb[4][128];
    int tid = threadIdx.x;
#pragma unroll
    for (int i = 0; i < 8; ++i)
        ((float4*)Wl)[tid + i * 256] = ((const float4*)Wlin)[tid + i * 256];
    __syncthreads();
    int lane = tid & 63, w = tid >> 6;
    for (int i = blockIdx.x * 4 + w; i < rows; i += gridDim.x * 4) {
        rb[w][lane]      = X[i * 128 + lane];
        rb[w][lane + 64] = X[i * 128 + 64 + lane];
        float acc = blin[lane];
#pragma unroll
        for (int k = 0; k < 128; ++k)
            acc = fmaf(rb[w][k], Wl[k * 64 + lane], acc);
        float m = acc;
#pragma unroll
        for (int off = 32; off >= 1; off >>= 1)
            m = fmaxf(m, __shfl_xor(m, off, 64));
        float p = expf(acc - m);
        float s = p;
#pragma unroll
        for (int off = 32; off >= 1; off >>= 1)
            s += __shfl_xor(s, off, 64);
        out[i * 64 + lane] = acc - m - logf(s);
    }
}

extern "C" void kernel_launch(void* const* d_in, const int* in_sizes, int n_in,
                              void* d_out, int out_size, void* d_ws, size_t ws_size,
                              hipStream_t stream) {
    const float* x    = (const float*)d_in[0];
    const int*   ei   = (const int*)  d_in[1];
    const int*   eib  = (const int*)  d_in[2];
    const float* lam  = (const float*)d_in[3];
    const int*   perm = (const int*)  d_in[4];
    const float* W0   = (const float*)d_in[5];
    const float* b0   = (const float*)d_in[6];
    const float* W1   = (const float*)d_in[7];
    const float* b1   = (const float*)d_in[8];
    const float* W2   = (const float*)d_in[9];
    const float* b2   = (const float*)d_in[10];
    const float* Wlin = (const float*)d_in[11];
    const float* blin = (const float*)d_in[12];
    float* out = (float*)d_out;

    const int* src  = ei;   const int* dst  = ei + NE;
    const int* srcb = eib;  const int* dstb = eib + NE;

    char* ws = (char*)d_ws;
    float* dinv    = (float*)ws;          // N
    float* deginv  = dinv + NN;           // N
    float* dinvb   = deginv + NN;         // N
    float* deginvb = dinvb + NN;          // N
    size_t big = (size_t)NN * 128;        // 6.4M floats per buffer
    float* P0 = (float*)(ws + (1u << 20));
    float* P1 = P0 + big;
    float* P2 = P1 + big;
    float* P3 = P2 + big;
    float* P4 = P3 + big;

    int gN   = (NN + 255) / 256;
    int gE   = (NE + 255) / 256;
    int gNC4 = (NN * 32 + 255) / 256;
    int gSc  = (NE * 32 + 255) / 256;
    int gMM  = (NN + 63) / 64;

    // degree norms for both edge sets
    k_deg_init<<<gN, 256, 0, stream>>>(dinv, dinvb, NN);
    k_deg_count<<<gE, 256, 0, stream>>>(dst, dstb, dinv, dinvb, NE);
    k_deg_fin<<<gN, 256, 0, stream>>>(dinv, deginv, dinvb, deginvb, NN);

    // x0 = x (mutable copy), x0_b = x0[perm], x_mix = lam*x0 + (1-lam)*x0_b
    hipMemcpyAsync(P0, x, big * sizeof(float), hipMemcpyDeviceToDevice, stream);
    k_permute<<<gNC4, 256, 0, stream>>>((const float4*)P0, perm, (float4*)P1, NN);
    k_mixcomb<<<gNC4, 256, 0, stream>>>((const float4*)P0, (const float4*)P1, lam,
                                        (float4*)P2, NN * 32);

    const float* Ws[2] = {W0, W1};
    const float* bs[2] = {b0, b1};
    float *x0 = P0, *x0b = P1, *xmix = P2, *A = P3, *B = P4;
    for (int L = 0; L < 2; ++L) {
        hipMemsetAsync(A, 0, big * sizeof(float), stream);
        hipMemsetAsync(B, 0, big * sizeof(float), stream);
        // S  = segment_sum over edges   of x0  (shared by h and x0-update)
        // Sb = segment_sum over edges_b of x0_b
        k_scatter<<<gSc, 256, 0, stream>>>(x0,  src,  dst,  dinv,  A, NE);
        k_scatter<<<gSc, 256, 0, stream>>>(x0b, srcb, dstb, dinvb, B, NE);
        // h    = relu((S  + xmix*deginv )@W + b) -> reuse x0b buffer (dead)
        // h_b  = relu((Sb + xmix*deginvb)@W + b) -> in place
        // x0'  = relu((S  + x0  *deginv )@W + b) -> in place
        k_mm_relu<<<gMM, 256, 0, stream>>>(A, xmix, deginv,  Ws[L], bs[L], x0b, NN);
        k_mm_relu<<<gMM, 256, 0, stream>>>(B, xmix, deginvb, Ws[L], bs[L], B,   NN);
        k_mm_relu<<<gMM, 256, 0, stream>>>(A, x0,   deginv,  Ws[L], bs[L], A,   NN);
        // x_mix = lam*h + (1-lam)*h_b
        k_mixcomb<<<gNC4, 256, 0, stream>>>((const float4*)x0b, (const float4*)B, lam,
                                            (float4*)xmix, NN * 32);
        // x0 <- x0' (pointer swap), x0_b = x0[perm]
        float* tmp = x0; x0 = A; A = tmp;
        k_permute<<<gNC4, 256, 0, stream>>>((const float4*)x0, perm, (float4*)x0b, NN);
    }

    // final layer (W2): h, h_b only
    hipMemsetAsync(A, 0, big * sizeof(float), stream);
    hipMemsetAsync(B, 0, big * sizeof(float), stream);
    k_scatter<<<gSc, 256, 0, stream>>>(x0,  src,  dst,  dinv,  A, NE);
    k_scatter<<<gSc, 256, 0, stream>>>(x0b, srcb, dstb, dinvb, B, NE);
    k_mm_relu<<<gMM, 256, 0, stream>>>(A, xmix, deginv,  W2, b2, x0b, NN);
    k_mm_relu<<<gMM, 256, 0, stream>>>(B, xmix, deginvb, W2, b2, B,   NN);
    k_mixcomb<<<gNC4, 256, 0, stream>>>((const float4*)x0b, (const float4*)B, lam,
                                        (float4*)xmix, NN * 32);

    // logits = x_out @ Wlin + blin ; log_softmax
    k_lin_lsm<<<12500, 256, 0, stream>>>(xmix, Wlin, blin, out, NN);
}

// Round 2
// 4287.250 us; speedup vs baseline: 2.7136x; 2.7136x over previous
//
#include <hip/hip_runtime.h>

#define NN 50000
#define NE 800000

// ---------------- degree kernels ----------------
__global__ void k_deg_init(float* a, float* b, int n) {
    int i = blockIdx.x * 256 + threadIdx.x;
    if (i < n) { a[i] = 1.0f; b[i] = 1.0f; }
}

__global__ void k_deg_count(const int* __restrict__ dst, const int* __restrict__ dstb,
                            float* __restrict__ deg, float* __restrict__ degb,
                            int* __restrict__ cntA, int* __restrict__ cntB, int e) {
    int i = blockIdx.x * 256 + threadIdx.x;
    if (i < e) {
        int d = dst[i], db = dstb[i];
        atomicAdd(&deg[d], 1.0f);
        atomicAdd(&degb[db], 1.0f);
        atomicAdd(&cntA[d], 1);
        atomicAdd(&cntB[db], 1);
    }
}

__global__ void k_deg_fin(float* dinv, float* deginv, float* dinvb, float* deginvb, int n) {
    int i = blockIdx.x * 256 + threadIdx.x;
    if (i < n) {
        float d = dinv[i];
        dinv[i]   = rsqrtf(d);
        deginv[i] = 1.0f / d;
        float db = dinvb[i];
        dinvb[i]   = rsqrtf(db);
        deginvb[i] = 1.0f / db;
    }
}

// ---------------- CSR build: scan + fill ----------------
__global__ __launch_bounds__(1024) void k_scan(const int* __restrict__ cnt,
                                               int* __restrict__ off, int n) {
    __shared__ int buf[1024];
    __shared__ int carry;
    int tid = threadIdx.x;
    if (tid == 0) carry = 0;
    __syncthreads();
    for (int base = 0; base < n; base += 1024) {
        int i = base + tid;
        int v = (i < n) ? cnt[i] : 0;
        buf[tid] = v;
        __syncthreads();
        for (int o = 1; o < 1024; o <<= 1) {
            int t = (tid >= o) ? buf[tid - o] : 0;
            __syncthreads();
            buf[tid] += t;
            __syncthreads();
        }
        int c = carry;
        if (i < n) off[i] = c + buf[tid] - v;   // exclusive
        __syncthreads();
        if (tid == 0) carry = c + buf[1023];
        __syncthreads();
    }
    if (tid == 0) off[n] = carry;
}

// csr record: .x = src node, .y = dinv[src] bits
__global__ void k_fill(const int* __restrict__ src, const int* __restrict__ dst,
                       const float* __restrict__ dinv, const int* __restrict__ off,
                       int* __restrict__ cur, int2* __restrict__ csr, int e) {
    int i = blockIdx.x * 256 + threadIdx.x;
    if (i < e) {
        int d = dst[i], s = src[i];
        int p = atomicAdd(&cur[d], 1);
        int2 rec;
        rec.x = s;
        rec.y = __float_as_int(dinv[s]);
        csr[off[d] + p] = rec;
    }
}

// ---------------- CSR gather (segment_sum, no atomics) ----------------
// 32 threads per node, float4 per thread; register accumulation, single write.
__global__ __launch_bounds__(256) void k_gather(
    const float4* __restrict__ x4, const int2* __restrict__ csr,
    const int* __restrict__ off, const float* __restrict__ dinv,
    float4* __restrict__ S, int n) {
    int t = blockIdx.x * 256 + threadIdx.x;
    int node = t >> 5, c4 = t & 31;
    if (node >= n) return;
    int b = off[node], e2 = off[node + 1];
    float4 acc = make_float4(0.f, 0.f, 0.f, 0.f);
    for (int i = b; i < e2; ++i) {
        int2 r = csr[i];
        float w = __int_as_float(r.y);
        float4 v = x4[r.x * 32 + c4];
        acc.x = fmaf(w, v.x, acc.x);
        acc.y = fmaf(w, v.y, acc.y);
        acc.z = fmaf(w, v.z, acc.z);
        acc.w = fmaf(w, v.w, acc.w);
    }
    float dn = dinv[node];
    acc.x *= dn; acc.y *= dn; acc.z *= dn; acc.w *= dn;
    S[node * 32 + c4] = acc;
}

// ---------------- permute / mix ----------------
__global__ void k_permute(const float4* __restrict__ in, const int* __restrict__ perm,
                          float4* __restrict__ out, int n) {
    int t = blockIdx.x * 256 + threadIdx.x;
    if (t < n * 32) {
        int i = t >> 5, c = t & 31;
        out[t] = in[perm[i] * 32 + c];
    }
}

__global__ void k_mixcomb(const float4* __restrict__ a, const float4* __restrict__ b,
                          const float* __restrict__ lamp, float4* __restrict__ o, int n4) {
    int t = blockIdx.x * 256 + threadIdx.x;
    if (t < n4) {
        float lam = lamp[0], ml = 1.0f - lam;
        float4 va = a[t], vb = b[t];
        o[t] = make_float4(fmaf(lam, va.x, ml * vb.x),
                           fmaf(lam, va.y, ml * vb.y),
                           fmaf(lam, va.z, ml * vb.z),
                           fmaf(lam, va.w, ml * vb.w));
    }
}

// ---------------- fused (S + self*deginv) @ W + b, relu ----------------
__global__ __launch_bounds__(256) void k_mm_relu(
    const float* __restrict__ S, const float* __restrict__ selfx,
    const float* __restrict__ deginv, const float* __restrict__ W,
    const float* __restrict__ bias, float* __restrict__ out, int rows) {
    __shared__ __align__(16) float Wl[128 * 128];   // 64 KiB
    __shared__ __align__(16) float rb[8][128];
    int tid = threadIdx.x;
#pragma unroll
    for (int i = 0; i < 16; ++i)
        ((float4*)Wl)[tid + i * 256] = ((const float4*)W)[tid + i * 256];
    int j = tid & 127, h = tid >> 7;
    int base = blockIdx.x * 64;
    __syncthreads();
    for (int t = 0; t < 8; ++t) {
        int r0 = base + t * 8;
        {   // stage 8 rows: row = S[row] + selfx[row]*deginv[row]
            int rr = tid >> 5, cc = tid & 31;
            int gi = r0 + rr;
            float4 rv = make_float4(0.f, 0.f, 0.f, 0.f);
            if (gi < rows) {
                float4 sv = ((const float4*)S)[gi * 32 + cc];
                float4 xv = ((const float4*)selfx)[gi * 32 + cc];
                float di = deginv[gi];
                rv = make_float4(fmaf(xv.x, di, sv.x), fmaf(xv.y, di, sv.y),
                                 fmaf(xv.z, di, sv.z), fmaf(xv.w, di, sv.w));
            }
            *((float4*)&rb[rr][cc * 4]) = rv;
        }
        __syncthreads();
        float bv = bias[j];
        float a0 = bv, a1 = bv, a2 = bv, a3 = bv;
#pragma unroll
        for (int k = 0; k < 128; ++k) {
            float wv = Wl[k * 128 + j];
            a0 = fmaf(rb[h * 4 + 0][k], wv, a0);
            a1 = fmaf(rb[h * 4 + 1][k], wv, a1);
            a2 = fmaf(rb[h * 4 + 2][k], wv, a2);
            a3 = fmaf(rb[h * 4 + 3][k], wv, a3);
        }
        int gi = r0 + h * 4;
        if (gi + 0 < rows) out[(gi + 0) * 128 + j] = fmaxf(a0, 0.f);
        if (gi + 1 < rows) out[(gi + 1) * 128 + j] = fmaxf(a1, 0.f);
        if (gi + 2 < rows) out[(gi + 2) * 128 + j] = fmaxf(a2, 0.f);
        if (gi + 3 < rows) out[(gi + 3) * 128 + j] = fmaxf(a3, 0.f);
        __syncthreads();
    }
}

// ---------------- final linear [128->64] + log_softmax ----------------
__global__ __launch_bounds__(256) void k_lin_lsm(
    const float* __restrict__ X, const float* __restrict__ Wlin,
    const float* __restrict__ blin, float* __restrict__ out, int rows) {
    __shared__ __align__(16) float Wl[128 * 64];    // 32 KiB
    __shared__ float rb[4][128];
    int tid = threadIdx.x;
#pragma unroll
    for (int i = 0; i < 8; ++i)
        ((float4*)Wl)[tid + i * 256] = ((const float4*)Wlin)[tid + i * 256];
    __syncthreads();
    int lane = tid & 63, w = tid >> 6;
    for (int i = blockIdx.x * 4 + w; i < rows; i += gridDim.x * 4) {
        rb[w][lane]      = X[i * 128 + lane];
        rb[w][lane + 64] = X[i * 128 + 64 + lane];
        float acc = blin[lane];
#pragma unroll
        for (int k = 0; k < 128; ++k)
            acc = fmaf(rb[w][k], Wl[k * 64 + lane], acc);
        float m = acc;
#pragma unroll
        for (int off = 32; off >= 1; off >>= 1)
            m = fmaxf(m, __shfl_xor(m, off, 64));
        float p = expf(acc - m);
        float s = p;
#pragma unroll
        for (int off = 32; off >= 1; off >>= 1)
            s += __shfl_xor(s, off, 64);
        out[i * 64 + lane] = acc - m - logf(s);
    }
}

extern "C" void kernel_launch(void* const* d_in, const int* in_sizes, int n_in,
                              void* d_out, int out_size, void* d_ws, size_t ws_size,
                              hipStream_t stream) {
    const float* x    = (const float*)d_in[0];
    const int*   ei   = (const int*)  d_in[1];
    const int*   eib  = (const int*)  d_in[2];
    const float* lam  = (const float*)d_in[3];
    const int*   perm = (const int*)  d_in[4];
    const float* W0   = (const float*)d_in[5];
    const float* b0   = (const float*)d_in[6];
    const float* W1   = (const float*)d_in[7];
    const float* b1   = (const float*)d_in[8];
    const float* W2   = (const float*)d_in[9];
    const float* b2   = (const float*)d_in[10];
    const float* Wlin = (const float*)d_in[11];
    const float* blin = (const float*)d_in[12];
    float* out = (float*)d_out;

    const int* src  = ei;   const int* dst  = ei + NE;
    const int* srcb = eib;  const int* dstb = eib + NE;

    // ---- workspace layout ----
    char* ws = (char*)d_ws;
    float* dinv    = (float*)ws;                  // N
    float* deginv  = dinv + NN;
    float* dinvb   = deginv + NN;
    float* deginvb = dinvb + NN;
    int* cntA = (int*)(deginvb + NN);             // N
    int* cntB = cntA + NN;
    int* curA = cntB + NN;
    int* curB = curA + NN;
    int* offA = curB + NN;                        // N+1
    int* offB = offA + (NN + 4);
    char* p = (char*)(offB + (NN + 4));
    p = (char*)(((size_t)p + 255) & ~(size_t)255);
    int2* csrA = (int2*)p;                        // E records (8B)
    int2* csrB = csrA + NE;
    p = (char*)(csrB + NE);
    p = (char*)(((size_t)p + 255) & ~(size_t)255);
    size_t big = (size_t)NN * 128;
    float* P0 = (float*)p;
    float* P1 = P0 + big;
    float* P2 = P1 + big;
    float* P3 = P2 + big;
    float* P4 = P3 + big;

    int gN   = (NN + 255) / 256;
    int gE   = (NE + 255) / 256;
    int gNC4 = (NN * 32 + 255) / 256;
    int gG   = (NN * 32 + 255) / 256;   // gather: 32 thr/node
    int gMM  = (NN + 63) / 64;

    // ---- degree norms + CSR build (once; reused by all 3 layers) ----
    hipMemsetAsync(cntA, 0, 4u * NN * sizeof(int), stream);   // cntA,cntB,curA,curB
    k_deg_init<<<gN, 256, 0, stream>>>(dinv, dinvb, NN);
    k_deg_count<<<gE, 256, 0, stream>>>(dst, dstb, dinv, dinvb, cntA, cntB, NE);
    k_deg_fin<<<gN, 256, 0, stream>>>(dinv, deginv, dinvb, deginvb, NN);
    k_scan<<<1, 1024, 0, stream>>>(cntA, offA, NN);
    k_scan<<<1, 1024, 0, stream>>>(cntB, offB, NN);
    k_fill<<<gE, 256, 0, stream>>>(src,  dst,  dinv,  offA, curA, csrA, NE);
    k_fill<<<gE, 256, 0, stream>>>(srcb, dstb, dinvb, offB, curB, csrB, NE);

    // x0 = x (mutable copy), x0_b = x0[perm], x_mix = lam*x0 + (1-lam)*x0_b
    hipMemcpyAsync(P0, x, big * sizeof(float), hipMemcpyDeviceToDevice, stream);
    k_permute<<<gNC4, 256, 0, stream>>>((const float4*)P0, perm, (float4*)P1, NN);
    k_mixcomb<<<gNC4, 256, 0, stream>>>((const float4*)P0, (const float4*)P1, lam,
                                        (float4*)P2, NN * 32);

    const float* Ws[2] = {W0, W1};
    const float* bs[2] = {b0, b1};
    float *x0 = P0, *x0b = P1, *xmix = P2, *A = P3, *B = P4;
    for (int L = 0; L < 2; ++L) {
        // S  = segment_sum over edges   of x0   (shared by h and x0-update)
        // Sb = segment_sum over edges_b of x0_b
        k_gather<<<gG, 256, 0, stream>>>((const float4*)x0,  csrA, offA, dinv,
                                         (float4*)A, NN);
        k_gather<<<gG, 256, 0, stream>>>((const float4*)x0b, csrB, offB, dinvb,
                                         (float4*)B, NN);
        // h    -> reuse x0b buffer (dead); h_b -> in place; x0' -> in place
        k_mm_relu<<<gMM, 256, 0, stream>>>(A, xmix, deginv,  Ws[L], bs[L], x0b, NN);
        k_mm_relu<<<gMM, 256, 0, stream>>>(B, xmix, deginvb, Ws[L], bs[L], B,   NN);
        k_mm_relu<<<gMM, 256, 0, stream>>>(A, x0,   deginv,  Ws[L], bs[L], A,   NN);
        // x_mix = lam*h + (1-lam)*h_b
        k_mixcomb<<<gNC4, 256, 0, stream>>>((const float4*)x0b, (const float4*)B, lam,
                                            (float4*)xmix, NN * 32);
        // x0 <- x0' (pointer swap), x0_b = x0[perm]
        float* tmp = x0; x0 = A; A = tmp;
        k_permute<<<gNC4, 256, 0, stream>>>((const float4*)x0, perm, (float4*)x0b, NN);
    }

    // final layer (W2): h, h_b only
    k_gather<<<gG, 256, 0, stream>>>((const float4*)x0,  csrA, offA, dinv,
                                     (float4*)A, NN);
    k_gather<<<gG, 256, 0, stream>>>((const float4*)x0b, csrB, offB, dinvb,
                                     (float4*)B, NN);
    k_mm_relu<<<gMM, 256, 0, stream>>>(A, xmix, deginv,  W2, b2, x0b, NN);
    k_mm_relu<<<gMM, 256, 0, stream>>>(B, xmix, deginvb, W2, b2, B,   NN);
    k_mixcomb<<<gNC4, 256, 0, stream>>>((const float4*)x0b, (const float4*)B, lam,
                                        (float4*)xmix, NN * 32);

    // logits = x_out @ Wlin + blin ; log_softmax
    k_lin_lsm<<<12500, 256, 0, stream>>>(xmix, Wlin, blin, out, NN);
}

// Round 3
// 1113.678 us; speedup vs baseline: 10.4464x; 3.8496x over previous
//
#include <hip/hip_runtime.h>

#define NN 50000
#define NE 800000

// ---------------- degree count (deg = 1 + in-degree) ----------------
__global__ void k_deg_count(const int* __restrict__ dst, const int* __restrict__ dstb,
                            int* __restrict__ cntA, int* __restrict__ cntB, int e) {
    int i = blockIdx.x * 256 + threadIdx.x;
    if (i < e) {
        atomicAdd(&cntA[dst[i]], 1);
        atomicAdd(&cntB[dstb[i]], 1);
    }
}

__global__ void k_deg_fin(const int* __restrict__ cntA, const int* __restrict__ cntB,
                          float* __restrict__ dinv, float* __restrict__ deginv,
                          float* __restrict__ dinvb, float* __restrict__ deginvb, int n) {
    int i = blockIdx.x * 256 + threadIdx.x;
    if (i < n) {
        float d = (float)(cntA[i] + 1);
        dinv[i]  = rsqrtf(d);  deginv[i]  = 1.0f / d;
        float db = (float)(cntB[i] + 1);
        dinvb[i] = rsqrtf(db); deginvb[i] = 1.0f / db;
    }
}

// ---------------- CSR build: scan + fill ----------------
__global__ __launch_bounds__(1024) void k_scan(const int* __restrict__ cnt,
                                               int* __restrict__ off, int n) {
    __shared__ int buf[1024];
    __shared__ int carry;
    int tid = threadIdx.x;
    if (tid == 0) carry = 0;
    __syncthreads();
    for (int base = 0; base < n; base += 1024) {
        int i = base + tid;
        int v = (i < n) ? cnt[i] : 0;
        buf[tid] = v;
        __syncthreads();
        for (int o = 1; o < 1024; o <<= 1) {
            int t = (tid >= o) ? buf[tid - o] : 0;
            __syncthreads();
            buf[tid] += t;
            __syncthreads();
        }
        int c = carry;
        if (i < n) off[i] = c + buf[tid] - v;   // exclusive
        __syncthreads();
        if (tid == 0) carry = c + buf[1023];
        __syncthreads();
    }
    if (tid == 0) off[n] = carry;
}

// csr record: .x = feature row to gather (perm-baked for branch b), .y = dinv[src] bits
__global__ void k_fill(const int* __restrict__ src, const int* __restrict__ dst,
                       const float* __restrict__ dinv, const int* __restrict__ perm,
                       const int* __restrict__ off, int* __restrict__ cur,
                       int2* __restrict__ csr, int e) {
    int i = blockIdx.x * 256 + threadIdx.x;
    if (i < e) {
        int d = dst[i], s = src[i];
        int p = atomicAdd(&cur[d], 1);
        int2 rec;
        rec.x = perm ? perm[s] : s;
        rec.y = __float_as_int(dinv[s]);
        csr[off[d] + p] = rec;
    }
}

// ---------------- CSR gather (segment_sum, no atomics) ----------------
__global__ __launch_bounds__(256) void k_gather(
    const float4* __restrict__ x4, const int2* __restrict__ csr,
    const int* __restrict__ off, const float* __restrict__ dinv,
    float4* __restrict__ S, int n) {
    int t = blockIdx.x * 256 + threadIdx.x;
    int node = t >> 5, c4 = t & 31;
    if (node >= n) return;
    int b = off[node], e2 = off[node + 1];
    float4 acc = make_float4(0.f, 0.f, 0.f, 0.f);
    for (int i = b; i < e2; ++i) {
        int2 r = csr[i];
        float w = __int_as_float(r.y);
        float4 v = x4[r.x * 32 + c4];
        acc.x = fmaf(w, v.x, acc.x);
        acc.y = fmaf(w, v.y, acc.y);
        acc.z = fmaf(w, v.z, acc.z);
        acc.w = fmaf(w, v.w, acc.w);
    }
    float dn = dinv[node];
    acc.x *= dn; acc.y *= dn; acc.z *= dn; acc.w *= dn;
    S[node * 32 + c4] = acc;
}

// ---------------- initial mix: xmix = lam*x + (1-lam)*x[perm] ----------------
__global__ void k_mixinit(const float4* __restrict__ x4, const int* __restrict__ perm,
                          const float* __restrict__ lamp, float4* __restrict__ o, int n) {
    int t = blockIdx.x * 256 + threadIdx.x;
    if (t < n * 32) {
        int i = t >> 5, c = t & 31;
        float lam = lamp[0], ml = 1.0f - lam;
        float4 a = x4[t];
        float4 b = x4[perm[i] * 32 + c];
        o[t] = make_float4(fmaf(lam, a.x, ml * b.x), fmaf(lam, a.y, ml * b.y),
                           fmaf(lam, a.z, ml * b.z), fmaf(lam, a.w, ml * b.w));
    }
}

// ---------------- fused layer kernel ----------------
// Per block: 32 output rows. 3 matmul passes sharing W in LDS:
//   pass1: h   = relu((A + xmix*dg )W + b)   (kept in registers)
//   pass2: h_b = relu((B + xmix*dgb)W + b);  xmix' = lam*h + (1-lam)*h_b  (in-place)
//   pass3: x0' = relu((A + x0 *dg )W + b)    (in-place over A)            [if do_x0]
// Thread tile: 4 rows x 4 cols. All LDS reads are b128 with half-wave broadcast.
#define ACCUM(ac, av)                                                          \
    ac.x = fmaf(av.x, w0.x, fmaf(av.y, w1.x, fmaf(av.z, w2.x, fmaf(av.w, w3.x, ac.x)))); \
    ac.y = fmaf(av.x, w0.y, fmaf(av.y, w1.y, fmaf(av.z, w2.y, fmaf(av.w, w3.y, ac.y)))); \
    ac.z = fmaf(av.x, w0.z, fmaf(av.y, w1.z, fmaf(av.z, w2.z, fmaf(av.w, w3.z, ac.z)))); \
    ac.w = fmaf(av.x, w0.w, fmaf(av.y, w1.w, fmaf(av.z, w2.w, fmaf(av.w, w3.w, ac.w))));

__global__ __launch_bounds__(256) void k_layer(
    const float* __restrict__ A, const float* __restrict__ B,
    float* __restrict__ xmix, const float* __restrict__ x0,
    const float* __restrict__ dg, const float* __restrict__ dgb,
    const float* __restrict__ W, const float* __restrict__ bias,
    const float* __restrict__ lamp, float* __restrict__ x0_out,
    int rows, int do_x0) {
    __shared__ __align__(16) float Wl[128 * 128];   // 64 KiB
    __shared__ __align__(16) float st[32 * 128];    // 16 KiB staged rows
    float4* Wl4 = (float4*)Wl;
    float4* st4 = (float4*)st;
    int tid = threadIdx.x;
#pragma unroll
    for (int i = 0; i < 16; ++i)
        Wl4[tid + i * 256] = ((const float4*)W)[tid + i * 256];
    int cg = tid & 31;      // col group: cols 4*cg..4*cg+3
    int rg = tid >> 5;      // row group: rows 4*rg..4*rg+3 (of 32)
    int row0 = blockIdx.x * 32;
    float lam = lamp[0];
    float4 bv = ((const float4*)bias)[cg];

    // stage: st[r][k] = Sv[row][k] + selfv[row][k] * dv[row]
    auto stage = [&](const float* Sv, const float* selfv, const float* dv) {
#pragma unroll
        for (int i = 0; i < 4; ++i) {
            int idx = tid + i * 256;            // 0..1023 float4 slots
            int r = idx >> 5, c = idx & 31;
            int gr = row0 + r;
            float4 v = make_float4(0.f, 0.f, 0.f, 0.f);
            if (gr < rows) {
                float4 sv = ((const float4*)Sv)[gr * 32 + c];
                float4 xv = ((const float4*)selfv)[gr * 32 + c];
                float d = dv[gr];
                v = make_float4(fmaf(xv.x, d, sv.x), fmaf(xv.y, d, sv.y),
                                fmaf(xv.z, d, sv.z), fmaf(xv.w, d, sv.w));
            }
            st4[idx] = v;
        }
    };

    auto mmpass = [&](float4* acc) {
        acc[0] = bv; acc[1] = bv; acc[2] = bv; acc[3] = bv;
#pragma unroll 4
        for (int k4 = 0; k4 < 32; ++k4) {
            float4 w0 = Wl4[(k4 * 4 + 0) * 32 + cg];
            float4 w1 = Wl4[(k4 * 4 + 1) * 32 + cg];
            float4 w2 = Wl4[(k4 * 4 + 2) * 32 + cg];
            float4 w3 = Wl4[(k4 * 4 + 3) * 32 + cg];
            float4 a0 = st4[(rg * 4 + 0) * 32 + k4];
            float4 a1 = st4[(rg * 4 + 1) * 32 + k4];
            float4 a2 = st4[(rg * 4 + 2) * 32 + k4];
            float4 a3 = st4[(rg * 4 + 3) * 32 + k4];
            ACCUM(acc[0], a0)
            ACCUM(acc[1], a1)
            ACCUM(acc[2], a2)
            ACCUM(acc[3], a3)
        }
    };

    // pass 1: h
    stage(A, xmix, dg);
    __syncthreads();
    float4 h[4];
    mmpass(h);
    __syncthreads();

    // pass 2: h_b, combine -> xmix'
    stage(B, xmix, dgb);
    __syncthreads();
    float4 g[4];
    mmpass(g);
    float ml = 1.0f - lam;
#pragma unroll
    for (int r = 0; r < 4; ++r) {
        int row = row0 + rg * 4 + r;
        if (row < rows) {
            float4 hv = h[r], gv = g[r];
            float4 o = make_float4(
                fmaf(lam, fmaxf(hv.x, 0.f), ml * fmaxf(gv.x, 0.f)),
                fmaf(lam, fmaxf(hv.y, 0.f), ml * fmaxf(gv.y, 0.f)),
                fmaf(lam, fmaxf(hv.z, 0.f), ml * fmaxf(gv.z, 0.f)),
                fmaf(lam, fmaxf(hv.w, 0.f), ml * fmaxf(gv.w, 0.f)));
            ((float4*)xmix)[row * 32 + cg] = o;
        }
    }
    __syncthreads();

    // pass 3: x0'
    if (do_x0) {
        stage(A, x0, dg);
        __syncthreads();
        mmpass(g);
#pragma unroll
        for (int r = 0; r < 4; ++r) {
            int row = row0 + rg * 4 + r;
            if (row < rows) {
                float4 gv = g[r];
                ((float4*)x0_out)[row * 32 + cg] =
                    make_float4(fmaxf(gv.x, 0.f), fmaxf(gv.y, 0.f),
                                fmaxf(gv.z, 0.f), fmaxf(gv.w, 0.f));
            }
        }
    }
}

// ---------------- final linear [128->64] + log_softmax ----------------
__global__ __launch_bounds__(256) void k_lin_lsm(
    const float* __restrict__ X, const float* __restrict__ Wlin,
    const float* __restrict__ blin, float* __restrict__ out, int rows) {
    __shared__ __align__(16) float Wl[128 * 64];
    __shared__ float rb[4][128];
    int tid = threadIdx.x;
#pragma unroll
    for (int i = 0; i < 8; ++i)
        ((float4*)Wl)[tid + i * 256] = ((const float4*)Wlin)[tid + i * 256];
    __syncthreads();
    int lane = tid & 63, w = tid >> 6;
    for (int i = blockIdx.x * 4 + w; i < rows; i += gridDim.x * 4) {
        rb[w][lane]      = X[i * 128 + lane];
        rb[w][lane + 64] = X[i * 128 + 64 + lane];
        float acc = blin[lane];
#pragma unroll
        for (int k = 0; k < 128; ++k)
            acc = fmaf(rb[w][k], Wl[k * 64 + lane], acc);
        float m = acc;
#pragma unroll
        for (int off = 32; off >= 1; off >>= 1)
            m = fmaxf(m, __shfl_xor(m, off, 64));
        float p = expf(acc - m);
        float s = p;
#pragma unroll
        for (int off = 32; off >= 1; off >>= 1)
            s += __shfl_xor(s, off, 64);
        out[i * 64 + lane] = acc - m - logf(s);
    }
}

extern "C" void kernel_launch(void* const* d_in, const int* in_sizes, int n_in,
                              void* d_out, int out_size, void* d_ws, size_t ws_size,
                              hipStream_t stream) {
    const float* x    = (const float*)d_in[0];
    const int*   ei   = (const int*)  d_in[1];
    const int*   eib  = (const int*)  d_in[2];
    const float* lam  = (const float*)d_in[3];
    const int*   perm = (const int*)  d_in[4];
    const float* W0   = (const float*)d_in[5];
    const float* b0   = (const float*)d_in[6];
    const float* W1   = (const float*)d_in[7];
    const float* b1   = (const float*)d_in[8];
    const float* W2   = (const float*)d_in[9];
    const float* b2   = (const float*)d_in[10];
    const float* Wlin = (const float*)d_in[11];
    const float* blin = (const float*)d_in[12];
    float* out = (float*)d_out;

    const int* src  = ei;   const int* dst  = ei + NE;
    const int* srcb = eib;  const int* dstb = eib + NE;

    // ---- workspace layout ----
    char* ws = (char*)d_ws;
    float* dinv    = (float*)ws;                  // N
    float* deginv  = dinv + NN;
    float* dinvb   = deginv + NN;
    float* deginvb = dinvb + NN;
    int* cntA = (int*)(deginvb + NN);             // N each: cntA,cntB,curA,curB
    int* cntB = cntA + NN;
    int* curA = cntB + NN;
    int* curB = curA + NN;
    int* offA = curB + NN;                        // N+1
    int* offB = offA + (NN + 4);
    char* p = (char*)(offB + (NN + 4));
    p = (char*)(((size_t)p + 255) & ~(size_t)255);
    int2* csrA = (int2*)p;                        // E records (8B)
    int2* csrB = csrA + NE;
    p = (char*)(csrB + NE);
    p = (char*)(((size_t)p + 255) & ~(size_t)255);
    size_t big = (size_t)NN * 128;
    float* P1 = (float*)p;                        // B (Sb) buffer
    float* P2 = P1 + big;                         // xmix
    float* P3 = P2 + big;                         // A / x0' ping
    float* P4 = P3 + big;                         // A / x0' pong

    int gN   = (NN + 255) / 256;
    int gE   = (NE + 255) / 256;
    int gNC4 = (NN * 32 + 255) / 256;
    int gL   = (NN + 31) / 32;

    // ---- degree norms + CSR build (once; reused by all 3 layers) ----
    hipMemsetAsync(cntA, 0, 4u * NN * sizeof(int), stream);
    k_deg_count<<<gE, 256, 0, stream>>>(dst, dstb, cntA, cntB, NE);
    k_deg_fin<<<gN, 256, 0, stream>>>(cntA, cntB, dinv, deginv, dinvb, deginvb, NN);
    k_scan<<<1, 1024, 0, stream>>>(cntA, offA, NN);
    k_scan<<<1, 1024, 0, stream>>>(cntB, offB, NN);
    k_fill<<<gE, 256, 0, stream>>>(src,  dst,  dinv,  nullptr, offA, curA, csrA, NE);
    k_fill<<<gE, 256, 0, stream>>>(srcb, dstb, dinvb, perm,    offB, curB, csrB, NE);

    // xmix = lam*x + (1-lam)*x[perm]
    k_mixinit<<<gNC4, 256, 0, stream>>>((const float4*)x, perm, lam, (float4*)P2, NN);

    // ---- layer 0 (x0 = x) ----
    k_gather<<<gNC4, 256, 0, stream>>>((const float4*)x, csrA, offA, dinv,  (float4*)P3, NN);
    k_gather<<<gNC4, 256, 0, stream>>>((const float4*)x, csrB, offB, dinvb, (float4*)P1, NN);
    k_layer<<<gL, 256, 0, stream>>>(P3, P1, P2, x, deginv, deginvb, W0, b0, lam, P3, NN, 1);

    // ---- layer 1 (x0 = P3) ----
    k_gather<<<gNC4, 256, 0, stream>>>((const float4*)P3, csrA, offA, dinv,  (float4*)P4, NN);
    k_gather<<<gNC4, 256, 0, stream>>>((const float4*)P3, csrB, offB, dinvb, (float4*)P1, NN);
    k_layer<<<gL, 256, 0, stream>>>(P4, P1, P2, P3, deginv, deginvb, W1, b1, lam, P4, NN, 1);

    // ---- final layer (x0 = P4, no x0' output) ----
    k_gather<<<gNC4, 256, 0, stream>>>((const float4*)P4, csrA, offA, dinv,  (float4*)P3, NN);
    k_gather<<<gNC4, 256, 0, stream>>>((const float4*)P4, csrB, offB, dinvb, (float4*)P1, NN);
    k_layer<<<gL, 256, 0, stream>>>(P3, P1, P2, P4, deginv, deginvb, W2, b2, lam, nullptr, NN, 0);

    // logits = xmix @ Wlin + blin ; log_softmax
    k_lin_lsm<<<12500, 256, 0, stream>>>(P2, Wlin, blin, out, NN);
}

// Round 4
// 571.317 us; speedup vs baseline: 20.3633x; 1.9493x over previous
//
#include <hip/hip_runtime.h>

#define NN 50000
#define NE 800000
#define NCH 49   // ceil(NN/1024)

typedef __attribute__((ext_vector_type(8))) short short8;
typedef __attribute__((ext_vector_type(4))) float f32x4;

// ---- bf16 helpers (RTNE) ----
__device__ inline float blo(unsigned u) { return __uint_as_float(u << 16); }
__device__ inline float bhi(unsigned u) { return __uint_as_float(u & 0xffff0000u); }
__device__ inline unsigned short f2b(float f) {
    unsigned u = __float_as_uint(f);
    u += 0x7fff + ((u >> 16) & 1);
    return (unsigned short)(u >> 16);
}
__device__ inline unsigned packrtne(float a, float b) {
    unsigned ua = __float_as_uint(a); ua += 0x7fff + ((ua >> 16) & 1);
    unsigned ub = __float_as_uint(b); ub += 0x7fff + ((ub >> 16) & 1);
    return (ua >> 16) | (ub & 0xffff0000u);
}

// ---------------- degree count (deg = 1 + in-degree) ----------------
__global__ void k_deg_count(const int* __restrict__ dst, const int* __restrict__ dstb,
                            int* __restrict__ cntA, int* __restrict__ cntB, int e) {
    int i = blockIdx.x * 256 + threadIdx.x;
    if (i < e) {
        atomicAdd(&cntA[dst[i]], 1);
        atomicAdd(&cntB[dstb[i]], 1);
    }
}

__global__ void k_deg_fin(const int* __restrict__ cntA, const int* __restrict__ cntB,
                          float* __restrict__ dinv, float* __restrict__ deginv,
                          float* __restrict__ dinvb, float* __restrict__ deginvb, int n) {
    int i = blockIdx.x * 256 + threadIdx.x;
    if (i < n) {
        float d = (float)(cntA[i] + 1);
        dinv[i]  = rsqrtf(d);  deginv[i]  = 1.0f / d;
        float db = (float)(cntB[i] + 1);
        dinvb[i] = rsqrtf(db); deginvb[i] = 1.0f / db;
    }
}

// ---------------- 3-phase parallel scan over both edge sets ----------------
__global__ __launch_bounds__(1024) void k_scan1(const int* __restrict__ cntA,
                                                const int* __restrict__ cntB,
                                                int* __restrict__ offA,
                                                int* __restrict__ offB,
                                                int* __restrict__ part) {
    __shared__ int buf[1024];
    int set = blockIdx.x / NCH, chunk = blockIdx.x % NCH;
    const int* cnt = set ? cntB : cntA;
    int* off = set ? offB : offA;
    int tid = threadIdx.x;
    int i = chunk * 1024 + tid;
    int v = (i < NN) ? cnt[i] : 0;
    buf[tid] = v;
    __syncthreads();
    for (int o = 1; o < 1024; o <<= 1) {
        int tv = (tid >= o) ? buf[tid - o] : 0;
        __syncthreads();
        buf[tid] += tv;
        __syncthreads();
    }
    if (i < NN) off[i] = buf[tid] - v;           // chunk-local exclusive
    if (tid == 1023) part[blockIdx.x] = buf[1023];
}

__global__ void k_scan2(int* __restrict__ part, int* __restrict__ offA,
                        int* __restrict__ offB) {
    int tid = threadIdx.x;      // 128 threads = 2 waves
    int lane = tid & 63, s = tid >> 6;
    int v = (lane < NCH) ? part[s * NCH + lane] : 0;
    int orig = v;
    for (int o = 1; o < 64; o <<= 1) {
        int t = __shfl_up(v, o, 64);
        if (lane >= o) v += t;
    }
    if (lane < NCH) part[s * NCH + lane] = v - orig;   // exclusive chunk base
    if (lane == NCH - 1) { if (s) offB[NN] = v; else offA[NN] = v; }
}

__global__ __launch_bounds__(1024) void k_scan3(int* __restrict__ offA,
                                                int* __restrict__ offB,
                                                const int* __restrict__ part) {
    int set = blockIdx.x / NCH, chunk = blockIdx.x % NCH;
    int* off = set ? offB : offA;
    int i = chunk * 1024 + threadIdx.x;
    if (i < NN) off[i] += part[blockIdx.x];
}

// ---------------- CSR fill, both edge sets, perm baked into B ----------------
__global__ void k_fill2(const int* __restrict__ src, const int* __restrict__ dst,
                        const int* __restrict__ srcb, const int* __restrict__ dstb,
                        const float* __restrict__ dinvA, const float* __restrict__ dinvB,
                        const int* __restrict__ perm,
                        const int* __restrict__ offA, const int* __restrict__ offB,
                        int* __restrict__ curA, int* __restrict__ curB,
                        int2* __restrict__ csrA, int2* __restrict__ csrB) {
    int i = blockIdx.x * 256 + threadIdx.x;
    if (i < NE) {
        int d = dst[i], s = src[i];
        int p = atomicAdd(&curA[d], 1);
        int2 rec; rec.x = s; rec.y = __float_as_int(dinvA[s]);
        csrA[offA[d] + p] = rec;
    } else if (i < 2 * NE) {
        i -= NE;
        int d = dstb[i], s = srcb[i];
        int p = atomicAdd(&curB[d], 1);
        int2 rec; rec.x = perm[s]; rec.y = __float_as_int(dinvB[s]);
        csrB[offB[d] + p] = rec;
    }
}

// ---------------- W -> bf16 transposed [col][k] ----------------
__global__ void k_prepw(const float* __restrict__ W0, const float* __restrict__ W1,
                        const float* __restrict__ W2, unsigned short* __restrict__ Wt) {
    int t = blockIdx.x * 256 + threadIdx.x;
    if (t < 3 * 16384) {
        int m = t >> 14, r = t & 16383;
        int k = r >> 7, c = r & 127;
        const float* W = (m == 0) ? W0 : (m == 1) ? W1 : W2;
        Wt[m * 16384 + c * 128 + k] = f2b(W[r]);
    }
}

// ---------------- x -> bf16 copies: xb = x, xmixb = lam*x + (1-lam)*x[perm] ----------------
__global__ void k_xinit(const float4* __restrict__ x4, const int* __restrict__ perm,
                        const float* __restrict__ lamp,
                        uint2* __restrict__ xb, uint2* __restrict__ xmixb) {
    int t = blockIdx.x * 256 + threadIdx.x;
    if (t < NN * 32) {
        int i = t >> 5, c = t & 31;
        float lam = lamp[0], ml = 1.0f - lam;
        float4 a = x4[t];
        float4 b = x4[(size_t)perm[i] * 32 + c];
        uint2 o1; o1.x = packrtne(a.x, a.y); o1.y = packrtne(a.z, a.w);
        xb[t] = o1;
        uint2 o2;
        o2.x = packrtne(fmaf(lam, a.x, ml * b.x), fmaf(lam, a.y, ml * b.y));
        o2.y = packrtne(fmaf(lam, a.z, ml * b.z), fmaf(lam, a.w, ml * b.w));
        xmixb[t] = o2;
    }
}

// ---------------- fused CSR gather for BOTH edge sets (bf16 in/out, f32 accum) ----------------
__global__ __launch_bounds__(256) void k_gather2(
    const unsigned short* __restrict__ xsrc,
    const int2* __restrict__ csrA, const int* __restrict__ offA, const float* __restrict__ dnA,
    const int2* __restrict__ csrB, const int* __restrict__ offB, const float* __restrict__ dnB,
    uint2* __restrict__ SA, uint2* __restrict__ SB) {
    int t = blockIdx.x * 256 + threadIdx.x;
    int node = t >> 5, c = t & 31;          // c: 4-bf16 chunk (8 B)
    const int2* csr; const int* off; const float* dn; uint2* S;
    if (node < NN) { csr = csrA; off = offA; dn = dnA; S = SA; }
    else           { node -= NN; csr = csrB; off = offB; dn = dnB; S = SB; }
    int b = off[node], e = off[node + 1];
    float a0 = 0.f, a1 = 0.f, a2 = 0.f, a3 = 0.f;
    int i = b;
    for (; i + 1 < e; i += 2) {
        int2 r0 = csr[i], r1 = csr[i + 1];
        uint2 v0 = *(const uint2*)(xsrc + (size_t)r0.x * 128 + c * 4);
        uint2 v1 = *(const uint2*)(xsrc + (size_t)r1.x * 128 + c * 4);
        float w0 = __int_as_float(r0.y), w1 = __int_as_float(r1.y);
        a0 = fmaf(w0, blo(v0.x), a0); a1 = fmaf(w0, bhi(v0.x), a1);
        a2 = fmaf(w0, blo(v0.y), a2); a3 = fmaf(w0, bhi(v0.y), a3);
        a0 = fmaf(w1, blo(v1.x), a0); a1 = fmaf(w1, bhi(v1.x), a1);
        a2 = fmaf(w1, blo(v1.y), a2); a3 = fmaf(w1, bhi(v1.y), a3);
    }
    if (i < e) {
        int2 r0 = csr[i];
        uint2 v0 = *(const uint2*)(xsrc + (size_t)r0.x * 128 + c * 4);
        float w0 = __int_as_float(r0.y);
        a0 = fmaf(w0, blo(v0.x), a0); a1 = fmaf(w0, bhi(v0.x), a1);
        a2 = fmaf(w0, blo(v0.y), a2); a3 = fmaf(w0, bhi(v0.y), a3);
    }
    float d = dn[node];
    uint2 o; o.x = packrtne(a0 * d, a1 * d); o.y = packrtne(a2 * d, a3 * d);
    S[(size_t)node * 32 + c] = o;
}

// ---------------- fused MFMA layer ----------------
// Block: 32 rows, 4 waves. Wave w: rowtile rt=w&1 (16 rows), coltiles (w>>1)*4..+3.
// LDS XOR-swizzle: 16B-slot index s for (r,k8): s = (r*16+k8) ^ (r&7)   [G4 fix]
__global__ __launch_bounds__(256) void k_layer(
    const unsigned short* __restrict__ A, const unsigned short* __restrict__ B,
    unsigned short* __restrict__ xmix, const unsigned short* __restrict__ x0,
    const float* __restrict__ dg, const float* __restrict__ dgb,
    const unsigned short* __restrict__ Wt, const float* __restrict__ bias,
    const float* __restrict__ lamp, unsigned short* __restrict__ x0_out, int do_x0) {
    __shared__ unsigned short Wl[16384];   // 32 KiB, [col][k] swizzled
    __shared__ unsigned short st[4096];    // 8 KiB,  [row][k] swizzled
    int tid = threadIdx.x;
    uint4* Wl16 = (uint4*)Wl;
    uint4* st16 = (uint4*)st;
    const uint4* Wg = (const uint4*)Wt;
#pragma unroll
    for (int i = 0; i < 8; ++i) {
        int idx = tid + i * 256;           // 2048 16B-slots
        int cc = idx >> 4;
        Wl16[idx ^ (cc & 7)] = Wg[idx];
    }
    int row0 = blockIdx.x * 32;
    float lam = lamp[0], ml = 1.0f - lam;
    int w = tid >> 6, lane = tid & 63;
    int rt = w & 1, ch = w >> 1;
    int lr = lane & 15, lk = lane >> 4;
    float bcol[4];
#pragma unroll
    for (int ct = 0; ct < 4; ++ct) bcol[ct] = bias[(ch * 4 + ct) * 16 + lr];

    auto stage = [&](const unsigned short* Sv, const unsigned short* selfv,
                     const float* dv) {
#pragma unroll
        for (int i = 0; i < 2; ++i) {
            int idx = tid + i * 256;       // 512 slots: r=idx>>4, k8=idx&15
            int r = idx >> 4, k8 = idx & 15;
            int gr = row0 + r;
            uint4 o = {0u, 0u, 0u, 0u};
            if (gr < NN) {
                uint4 sv = *(const uint4*)(Sv + (size_t)gr * 128 + k8 * 8);
                uint4 xv = *(const uint4*)(selfv + (size_t)gr * 128 + k8 * 8);
                float d = dv[gr];
                o.x = packrtne(fmaf(blo(xv.x), d, blo(sv.x)), fmaf(bhi(xv.x), d, bhi(sv.x)));
                o.y = packrtne(fmaf(blo(xv.y), d, blo(sv.y)), fmaf(bhi(xv.y), d, bhi(sv.y)));
                o.z = packrtne(fmaf(blo(xv.z), d, blo(sv.z)), fmaf(bhi(xv.z), d, bhi(sv.z)));
                o.w = packrtne(fmaf(blo(xv.w), d, blo(sv.w)), fmaf(bhi(xv.w), d, bhi(sv.w)));
            }
            st16[idx ^ (r & 7)] = o;
        }
    };

    auto mmpass = [&](f32x4* acc) {
#pragma unroll
        for (int ct = 0; ct < 4; ++ct) {
            float bv = bcol[ct];
            acc[ct] = (f32x4){bv, bv, bv, bv};
        }
#pragma unroll
        for (int kt = 0; kt < 4; ++kt) {
            int k8 = kt * 4 + lk;
            int ar = rt * 16 + lr;
            short8 af = *(const short8*)&st[((ar * 16 + k8) ^ (ar & 7)) * 8];
#pragma unroll
            for (int ct = 0; ct < 4; ++ct) {
                int bc = (ch * 4 + ct) * 16 + lr;
                short8 bf = *(const short8*)&Wl[((bc * 16 + k8) ^ (bc & 7)) * 8];
                acc[ct] = __builtin_amdgcn_mfma_f32_16x16x32_bf16(af, bf, acc[ct], 0, 0, 0);
            }
        }
    };

    f32x4 h[4], g[4];
    // pass 1: h = (A + xmix*dg) W + b
    stage(A, xmix, dg);
    __syncthreads();
    mmpass(h);
    __syncthreads();
    // pass 2: g = (B + xmix*dgb) W + b ; xmix' = lam*relu(h)+(1-lam)*relu(g)
    stage(B, xmix, dgb);
    __syncthreads();
    mmpass(g);
#pragma unroll
    for (int ct = 0; ct < 4; ++ct) {
        int col = (ch * 4 + ct) * 16 + lr;
#pragma unroll
        for (int j = 0; j < 4; ++j) {
            int gr = row0 + rt * 16 + lk * 4 + j;
            if (gr < NN) {
                float hv = fmaxf(h[ct][j], 0.f), gv = fmaxf(g[ct][j], 0.f);
                xmix[(size_t)gr * 128 + col] = f2b(fmaf(lam, hv, ml * gv));
            }
        }
    }
    // pass 3: x0' = relu((A + x0*dg) W + b)
    if (do_x0) {
        __syncthreads();
        stage(A, x0, dg);
        __syncthreads();
        mmpass(g);
#pragma unroll
        for (int ct = 0; ct < 4; ++ct) {
            int col = (ch * 4 + ct) * 16 + lr;
#pragma unroll
            for (int j = 0; j < 4; ++j) {
                int gr = row0 + rt * 16 + lk * 4 + j;
                if (gr < NN)
                    x0_out[(size_t)gr * 128 + col] = f2b(fmaxf(g[ct][j], 0.f));
            }
        }
    }
}

// ---------------- final linear [128->64] + log_softmax (bf16 in, f32 out) ----------------
__global__ __launch_bounds__(256) void k_lin_lsm(
    const unsigned short* __restrict__ X, const float* __restrict__ Wlin,
    const float* __restrict__ blin, float* __restrict__ out) {
    __shared__ __align__(16) float Wl[128 * 64];
    __shared__ float rb[4][128];
    int tid = threadIdx.x;
#pragma unroll
    for (int i = 0; i < 8; ++i)
        ((float4*)Wl)[tid + i * 256] = ((const float4*)Wlin)[tid + i * 256];
    __syncthreads();
    int lane = tid & 63, w = tid >> 6;
    for (int i = blockIdx.x * 4 + w; i < NN; i += gridDim.x * 4) {
        unsigned u = *(const unsigned*)(X + (size_t)i * 128 + lane * 2);
        rb[w][lane * 2]     = blo(u);
        rb[w][lane * 2 + 1] = bhi(u);
        float acc = blin[lane];
#pragma unroll
        for (int k = 0; k < 128; ++k)
            acc = fmaf(rb[w][k], Wl[k * 64 + lane], acc);
        float m = acc;
#pragma unroll
        for (int off = 32; off >= 1; off >>= 1)
            m = fmaxf(m, __shfl_xor(m, off, 64));
        float p = expf(acc - m);
        float s = p;
#pragma unroll
        for (int off = 32; off >= 1; off >>= 1)
            s += __shfl_xor(s, off, 64);
        out[(size_t)i * 64 + lane] = acc - m - logf(s);
    }
}

extern "C" void kernel_launch(void* const* d_in, const int* in_sizes, int n_in,
                              void* d_out, int out_size, void* d_ws, size_t ws_size,
                              hipStream_t stream) {
    const float* x    = (const float*)d_in[0];
    const int*   ei   = (const int*)  d_in[1];
    const int*   eib  = (const int*)  d_in[2];
    const float* lam  = (const float*)d_in[3];
    const int*   perm = (const int*)  d_in[4];
    const float* W0   = (const float*)d_in[5];
    const float* b0   = (const float*)d_in[6];
    const float* W1   = (const float*)d_in[7];
    const float* b1   = (const float*)d_in[8];
    const float* W2   = (const float*)d_in[9];
    const float* b2   = (const float*)d_in[10];
    const float* Wlin = (const float*)d_in[11];
    const float* blin = (const float*)d_in[12];
    float* out = (float*)d_out;

    const int* src  = ei;   const int* dst  = ei + NE;
    const int* srcb = eib;  const int* dstb = eib + NE;

    // ---- workspace layout ----
    char* ws = (char*)d_ws;
    float* dinv    = (float*)ws;                  // N each
    float* deginv  = dinv + NN;
    float* dinvb   = deginv + NN;
    float* deginvb = dinvb + NN;
    int* cntA = (int*)(deginvb + NN);             // N each: cntA,cntB,curA,curB
    int* cntB = cntA + NN;
    int* curA = cntB + NN;
    int* curB = curA + NN;
    int* offA = curB + NN;                        // N+1 (+pad)
    int* offB = offA + (NN + 4);
    int* part = offB + (NN + 4);                  // 98 (+pad)
    char* p = (char*)(part + 128);
    p = (char*)(((size_t)p + 255) & ~(size_t)255);
    int2* csrA = (int2*)p;
    int2* csrB = csrA + NE;
    p = (char*)(csrB + NE);
    p = (char*)(((size_t)p + 255) & ~(size_t)255);
    unsigned short* Wt    = (unsigned short*)p;   // 3 * 16384 bf16
    unsigned short* xb    = Wt + 3 * 16384;       // N*128 bf16 each
    unsigned short* xmixb = xb + (size_t)NN * 128;
    unsigned short* AG    = xmixb + (size_t)NN * 128;
    unsigned short* BG    = AG + (size_t)NN * 128;
    unsigned short* X1    = BG + (size_t)NN * 128;
    unsigned short* X2    = X1 + (size_t)NN * 128;

    int gN = (NN + 255) / 256;
    int gE = (NE + 255) / 256;
    int gL = (NN + 31) / 32;

    // ---- degree norms + CSR build (once; reused by all 3 layers) ----
    hipMemsetAsync(cntA, 0, 4u * NN * sizeof(int), stream);
    k_deg_count<<<gE, 256, 0, stream>>>(dst, dstb, cntA, cntB, NE);
    k_deg_fin<<<gN, 256, 0, stream>>>(cntA, cntB, dinv, deginv, dinvb, deginvb, NN);
    k_scan1<<<2 * NCH, 1024, 0, stream>>>(cntA, cntB, offA, offB, part);
    k_scan2<<<1, 128, 0, stream>>>(part, offA, offB);
    k_scan3<<<2 * NCH, 1024, 0, stream>>>(offA, offB, part);
    k_fill2<<<(2 * NE + 255) / 256, 256, 0, stream>>>(src, dst, srcb, dstb, dinv, dinvb,
                                                      perm, offA, offB, curA, curB,
                                                      csrA, csrB);
    k_prepw<<<192, 256, 0, stream>>>(W0, W1, W2, Wt);
    k_xinit<<<(NN * 32) / 256, 256, 0, stream>>>((const float4*)x, perm, lam,
                                                 (uint2*)xb, (uint2*)xmixb);

    // ---- layer 0 ----
    k_gather2<<<(2 * NN * 32) / 256, 256, 0, stream>>>(xb, csrA, offA, dinv,
                                                       csrB, offB, dinvb,
                                                       (uint2*)AG, (uint2*)BG);
    k_layer<<<gL, 256, 0, stream>>>(AG, BG, xmixb, xb, deginv, deginvb,
                                    Wt, b0, lam, X1, 1);
    // ---- layer 1 ----
    k_gather2<<<(2 * NN * 32) / 256, 256, 0, stream>>>(X1, csrA, offA, dinv,
                                                       csrB, offB, dinvb,
                                                       (uint2*)AG, (uint2*)BG);
    k_layer<<<gL, 256, 0, stream>>>(AG, BG, xmixb, X1, deginv, deginvb,
                                    Wt + 16384, b1, lam, X2, 1);
    // ---- layer 2 (no x0 branch) ----
    k_gather2<<<(2 * NN * 32) / 256, 256, 0, stream>>>(X2, csrA, offA, dinv,
                                                       csrB, offB, dinvb,
                                                       (uint2*)AG, (uint2*)BG);
    k_layer<<<gL, 256, 0, stream>>>(AG, BG, xmixb, X2, deginv, deginvb,
                                    Wt + 32768, b2, lam, (unsigned short*)nullptr, 0);

    // ---- logits + log_softmax ----
    k_lin_lsm<<<12500, 256, 0, stream>>>(xmixb, Wlin, blin, out);
}